// Round 14
// baseline (189.812 us; speedup 1.0000x reference)
//
#include <hip/hip_runtime.h>

// Problem constants (fixed by reference)
#define B_    2
#define NH_   4
#define T_    8
#define H_    14
#define W_    14
#define HW_   196             // H*W
#define HD_   96
#define DIM_  384
#define N_    1568            // T*H*W
#define BH_   (B_*NH_)        // 8
#define BN_   (B_*N_)         // 3136
#define BHN_  (BH_*N_)        // 12544
#define CAUG_ 160             // 96 + 36 one-hot/bias + 28 pad

typedef unsigned short bf_t;
typedef unsigned int   u32;
typedef __attribute__((ext_vector_type(8))) short bf16x8;
typedef __attribute__((ext_vector_type(4))) float f32x4;

#define LOG2E 1.4426950408889634f
#define QSCALE_LOG2E 0.14724445f   /* 96^-0.5 * log2(e) */

static __device__ __forceinline__ float lo16(u32 v){ union{u32 i; float f;}x; x.i = v<<16;           return x.f; }
static __device__ __forceinline__ float hi16(u32 v){ union{u32 i; float f;}x; x.i = v & 0xffff0000u; return x.f; }
static __device__ __forceinline__ float b2f(bf_t v){ union{u32 i; float f;}x; x.i = ((u32)v)<<16;    return x.f; }
static __device__ __forceinline__ bf_t  f2b(float f){
  union{float f; u32 i;} x; x.f = f;
  return (bf_t)((x.i + 0x7fffu + ((x.i>>16)&1u)) >> 16);   // RNE
}
static __device__ __forceinline__ u32 pack2(float a, float b){
  return (u32)f2b(a) | ((u32)f2b(b) << 16);
}
// fragment-tile index for a row-major [R][384] matrix element (row, k)
static __device__ __forceinline__ size_t ftidx(int row, int k){
  return ((((size_t)(row>>4))*12 + (k>>5))*64 + ((k>>3)&3)*16 + (row&15))*8 + (k&7);
}

// ---------------------------------------------------------------------------
// K0: cast x / qkv_w / proj_w fp32 -> bf16 in FRAGMENT-TILED layout, plus
// conv-weight transpose [96][27]->[27][96] fp32 (last 31 blocks).
// R24 (verified -2.8us): tile-per-wave; one wave owns one 16x32 fragment
// tile -> lane l writes 16B contiguous, wave writes a coalesced 1KB tile.
// ---------------------------------------------------------------------------
#define NA_ (BN_*DIM_)        // 1,204,224
#define NB_ (3*DIM_*DIM_)     //   442,368
#define NC_ (DIM_*DIM_)       //   147,456
#define TILES_X 2352          // (3136/16)*(384/32)
#define TILES_B 864           // (1152/16)*12
#define TILES_C 288           // (384/16)*12
#define CAST_MBLOCKS ((TILES_X+TILES_B+TILES_C)/4)   // 876 exactly

__global__ __launch_bounds__(256) void k_cast(
    const float* __restrict__ a, bf_t* __restrict__ ad,
    const float* __restrict__ b, bf_t* __restrict__ bd,
    const float* __restrict__ c, bf_t* __restrict__ cd,
    const float* __restrict__ wq, const float* __restrict__ wk,
    const float* __restrict__ wv, float* __restrict__ tq,
    float* __restrict__ tk, float* __restrict__ tv){
  if (blockIdx.x < CAST_MBLOCKS){
    const int tile = blockIdx.x*4 + (threadIdx.x >> 6);
    const int lane = threadIdx.x & 63;
    const float* src; bf_t* dst; int tl;
    if (tile < TILES_X)                { src = a; dst = ad; tl = tile; }
    else if (tile < TILES_X + TILES_B) { src = b; dst = bd; tl = tile - TILES_X; }
    else                               { src = c; dst = cd; tl = tile - TILES_X - TILES_B; }
    const int mt = tl / 12, kt = tl % 12;
    const int row = mt*16 + (lane & 15);
    const int k0  = kt*32 + (lane >> 4)*8;
    const float4 v0 = *(const float4*)(src + (size_t)row*DIM_ + k0);
    const float4 v1 = *(const float4*)(src + (size_t)row*DIM_ + k0 + 4);
    const u32 w0 = pack2(v0.x, v0.y), w1 = pack2(v0.z, v0.w);
    const u32 w2 = pack2(v1.x, v1.y), w3 = pack2(v1.z, v1.w);
    *(uint4*)(dst + (size_t)tl*512 + lane*8) = make_uint4(w0, w1, w2, w3);
  } else {
    const int idx = (blockIdx.x - CAST_MBLOCKS)*256 + threadIdx.x;
    if (idx >= 3*HD_*27) return;
    const int t = idx / (HD_*27), rem = idx % (HD_*27);
    const int ch = rem / 27, j = rem % 27;
    const float* s = (t==0)? wq : (t==1)? wk : wv;
    float* d       = (t==0)? tq : (t==1)? tk : tv;
    d[j*HD_ + ch] = s[ch*27 + j];
  }
}

// ---------------------------------------------------------------------------
// K1: QKV GEMM via MFMA, fragment-tiled operands.
// R26: per-wave row-tile halved 32->16 (acc[4], 1 A-load/k0). Grid (49,9)
// x4 waves was 1764 waves on 1024 SIMDs = 1.7/SIMD -- TLP-starved. Now
// (98,9) -> 3528 waves = 3.4/SIMD. B-panels are L2-hot so the halved
// B-reuse costs little. Scalar-store epilogue kept (R21/22: LDS staging
// measured +1.5us).
// ---------------------------------------------------------------------------
__global__ __launch_bounds__(256) void k_qkv(const bf_t* __restrict__ Xt,
    const bf_t* __restrict__ Wt,
    bf_t* __restrict__ q, bf_t* __restrict__ k, bf_t* __restrict__ v){
  const int wid = threadIdx.x >> 6, lane = threadIdx.x & 63;
  const int wr = wid & 1, wc = wid >> 1;
  const int nl = lane & 15, quad = lane >> 4;
  const int r0 = blockIdx.x*32 + wr*16;
  const int mt0 = r0 >> 4;
  const int nt0 = blockIdx.y*8 + wc*4;
  f32x4 acc[4];
  #pragma unroll
  for (int j = 0; j < 4; ++j) acc[j] = (f32x4){0.f,0.f,0.f,0.f};
  const bf_t* A0 = Xt + ((size_t)mt0*12*64 + lane)*8;
  const bf_t* B0 = Wt + ((size_t)nt0*12*64 + lane)*8;
  #pragma unroll 2
  for (int k0 = 0; k0 < 12; ++k0){
    const bf16x8 a0 = *(const bf16x8*)(A0 + k0*512);
    bf16x8 bf[4];
    #pragma unroll
    for (int j = 0; j < 4; ++j) bf[j] = *(const bf16x8*)(B0 + (size_t)(j*12 + k0)*512);
    #pragma unroll
    for (int j = 0; j < 4; ++j)
      acc[j] = __builtin_amdgcn_mfma_f32_16x16x32_bf16(a0, bf[j], acc[j], 0, 0, 0);
  }
  #pragma unroll
  for (int r = 0; r < 4; ++r){
    const int m  = r0 + quad*4 + r;
    const int bb = m / N_, nn = m % N_;
    #pragma unroll
    for (int j = 0; j < 4; ++j){
      const int col = (nt0 + j)*16 + nl;
      const int s = col / DIM_, rem = col - s*DIM_;
      const int head = rem / HD_, hc = rem % HD_;
      bf_t* dst = (s==0) ? q : (s==1) ? k : v;
      dst[((size_t)(bb*NH_ + head)*N_ + nn)*HD_ + hc] = f2b(acc[j][r]);
    }
  }
}

static __device__ __forceinline__ void ln_butterfly(
    float v0, float v1, float& mean, float& rstd){
  float s  = v0 + v1;
  float s2 = v0*v0 + v1*v1;
  #pragma unroll
  for (int off = 32; off > 0; off >>= 1){
    s  += __shfl_xor(s,  off);
    s2 += __shfl_xor(s2, off);
  }
  mean = s * (1.f/HD_);
  const float var = fmaxf(s2*(1.f/HD_) - mean*mean, 0.f);
  rstd = rsqrtf(var + 1e-6f);
}

// ---------------------------------------------------------------------------
// K2: LDS-slab pooled conv+LN, 16 tokens/block (4 waves x 4 tokens).
// Halo slab 162 rows (3t x 3h x 18w) x 96ch bf16 = 31.1 KB.
// R16 form (best measured). Ledger: R14 forced-occupancy spill (-),
// R17 deep pipeline (-), R19 XCD pinning (FETCH 22->3.9MB, timing-neutral).
// Observed env variance on identical code: 47.6-55.8us.
// ---------------------------------------------------------------------------
union PoolSM {
  bf_t  slab[162][HD_];       // 31,104 B  (phase 1)
  float qtmp[4][4][HD_];      //  6,144 B  (phase 2, sec 0; per-wave)
  u32   vres[16][48];         //  3,072 B  (phase 2, sec 2)
};

__global__ __launch_bounds__(256) void k_pool_slab(
    const bf_t* __restrict__ qr_, const bf_t* __restrict__ kr_, const bf_t* __restrict__ vr_,
    const float* __restrict__ wtq, const float* __restrict__ wtk, const float* __restrict__ wtv,
    const float* __restrict__ gq, const float* __restrict__ bq,
    const float* __restrict__ gk, const float* __restrict__ bk,
    const float* __restrict__ gv, const float* __restrict__ bv,
    const float* __restrict__ rph, const float* __restrict__ rpw,
    const float* __restrict__ rpt,
    bf_t* __restrict__ qp, bf_t* __restrict__ Qaug,
    bf_t* __restrict__ Kt, bf_t* __restrict__ Vtt){
  __shared__ __align__(16) PoolSM sm;
  const int wid = threadIdx.x >> 6, lane = threadIdx.x & 63;
  const int sec = blockIdx.x / 784;
  const int rr_ = blockIdx.x % 784;
  const int bh = rr_ / 98, tok0 = (rr_ % 98)*16;
  const bf_t*  src = (sec==0)? qr_ : (sec==1)? kr_ : vr_;
  const float* wt  = (sec==0)? wtq : (sec==1)? wtk : wtv;
  const float* g   = (sec==0)? gq  : (sec==1)? gk  : gv;
  const float* be  = (sec==0)? bq  : (sec==1)? bk  : bv;
  const bf_t* base = src + (size_t)bh*N_*HD_;

  // per-lane channel pair; first weight trio + LN params overlap staging
  const int c0 = (lane < 48) ? 2*lane : 0;
  float2 wcur[3], wnxt[3];
  #pragma unroll
  for (int dw = 0; dw < 3; ++dw) wcur[dw] = *(const float2*)(wt + dw*HD_ + c0);
  const float gg0 = g[c0], gg1 = g[c0+1], be0 = be[c0], be1 = be[c0+1];

  // ---- staging: batched loads into regs, then LDS writes (vmcnt pipeline) --
  {
    uint4 stg[8];
    #pragma unroll
    for (int it = 0; it < 8; ++it){
      const int li = threadIdx.x + it*256;
      const int lc = (li < 162*12) ? li : (162*12 - 1);
      const int rw = lc / 12, ss = lc % 12;
      const int aa = rw/54, bb2 = (rw%54)/18, cc = rw%18;
      int nn = tok0 + (aa-1)*HW_ + (bb2-1)*W_ + (cc-1);
      nn = min(max(nn, 0), N_-1);
      stg[it] = *(const uint4*)(base + (size_t)nn*HD_ + ss*8);
    }
    #pragma unroll
    for (int it = 0; it < 8; ++it){
      const int li = threadIdx.x + it*256;
      if (li < 162*12){
        const int rw = li / 12, ss = li % 12;
        *(uint4*)&sm.slab[rw][ss*8] = stg[it];
      }
    }
  }
  __syncthreads();

  // token coordinates (wave-uniform) + 27-bit validity masks
  int tt[4], hh[4], ww[4];
  u32 mr[4];
  #pragma unroll
  for (int tk = 0; tk < 4; ++tk){
    const int n = tok0 + wid*4 + tk;
    tt[tk] = n / HW_;
    const int rm = n % HW_;
    hh[tk] = rm / W_; ww[tk] = rm % W_;
    const u32 wb = (ww[tk] > 0 ? 1u : 0u) | 2u | (ww[tk] < W_-1 ? 4u : 0u);
    const u32 h9 = (hh[tk] > 0 ? wb : 0u) | (wb << 3) | (hh[tk] < H_-1 ? (wb << 6) : 0u);
    mr[tk] = (tt[tk] > 0 ? h9 : 0u) | (h9 << 9) | (tt[tk] < T_-1 ? (h9 << 18) : 0u);
  }

  // ---- phase 1: conv, software-pipelined row reads ----
  float v0[4] = {0.f,0.f,0.f,0.f}, v1[4] = {0.f,0.f,0.f,0.f};
  u32 rr[6], rrn[6];
  #pragma unroll
  for (int s = 0; s < 6; ++s) rr[s] = *(const u32*)&sm.slab[wid*4 + s][c0];
  #pragma unroll 1
  for (int j9 = 0; j9 < 9; ++j9){
    if (j9 < 8){
      const int jn = j9 + 1;
      const int rbn = (jn/3)*54 + (jn%3)*18 + wid*4;
      #pragma unroll
      for (int s = 0; s < 6; ++s) rrn[s] = *(const u32*)&sm.slab[rbn + s][c0];
      #pragma unroll
      for (int dw = 0; dw < 3; ++dw)
        wnxt[dw] = *(const float2*)(wt + (jn*3 + dw)*HD_ + c0);
    }
    #pragma unroll
    for (int tk = 0; tk < 4; ++tk){
      #pragma unroll
      for (int dw = 0; dw < 3; ++dw){
        const u32 d = (mr[tk] & (1u << dw)) ? rr[tk+dw] : 0u;
        v0[tk] = fmaf(wcur[dw].x, lo16(d), v0[tk]);
        v1[tk] = fmaf(wcur[dw].y, hi16(d), v1[tk]);
      }
      mr[tk] >>= 3;
    }
    #pragma unroll
    for (int s = 0; s < 6; ++s) rr[s] = rrn[s];
    #pragma unroll
    for (int dw = 0; dw < 3; ++dw) wcur[dw] = wnxt[dw];
  }
  // LayerNorm per token (results stay in v0/v1)
  #pragma unroll
  for (int tk = 0; tk < 4; ++tk){
    float a = v0[tk], b = v1[tk];
    if (lane >= 48){ a = 0.f; b = 0.f; }
    float mean, rstd;
    ln_butterfly(a, b, mean, rstd);
    v0[tk] = (a - mean)*rstd*gg0 + be0;
    v1[tk] = (b - mean)*rstd*gg1 + be1;
  }

  // ---- phase 2: outputs (qtmp/vres overlay slab; barrier before overlay) --
  if (sec == 0){
    __syncthreads();                              // slab -> qtmp overlay
    #pragma unroll
    for (int tk = 0; tk < 4; ++tk){
      const int n = tok0 + wid*4 + tk;
      const int token = bh*N_ + n;
      if (lane < 48){
        ((u32*)qp)  [(size_t)token*48 + lane] = pack2(v0[tk], v1[tk]);
        ((u32*)Qaug)[(size_t)token*80 + lane] = pack2(v0[tk]*QSCALE_LOG2E, v1[tk]*QSCALE_LOG2E);
        *(float2*)&sm.qtmp[wid][tk][c0] = make_float2(v0[tk], v1[tk]);
      }
    }
    // qtmp written/read by the SAME wave -> ordered by lgkmcnt, no barrier
    #pragma unroll
    for (int tk = 0; tk < 4; ++tk){
      const int n = tok0 + wid*4 + tk;
      const int token = bh*N_ + n;
      if (lane < 36){
        const float* tb; int idx;
        if (lane < 14)      { tb = rph; idx = hh[tk] - lane      + 13; }
        else if (lane < 28) { tb = rpw; idx = ww[tk] - (lane-14) + 13; }
        else                { tb = rpt; idx = tt[tk] - (lane-28) +  7; }
        const float4* t4 = (const float4*)(tb + (size_t)idx*HD_);
        const float4* q4 = (const float4*)&sm.qtmp[wid][tk][0];
        float ap[4] = {0.f, 0.f, 0.f, 0.f};
        #pragma unroll
        for (int i = 0; i < 24; ++i){
          const float4 rv = t4[i];
          const float4 qv = q4[i];                 // ds_read_b128 broadcast
          ap[i & 3] = fmaf(qv.x, rv.x,
                      fmaf(qv.y, rv.y,
                      fmaf(qv.z, rv.z,
                      fmaf(qv.w, rv.w, ap[i & 3]))));
        }
        const float acc = (ap[0] + ap[1]) + (ap[2] + ap[3]);
        Qaug[(size_t)token*CAUG_ + HD_ + lane] = f2b(acc * LOG2E);
      } else {
        Qaug[(size_t)token*CAUG_ + HD_ + lane] = 0;
      }
    }
  } else if (sec == 1){
    // no LDS use in this branch -> no barrier needed
    #pragma unroll
    for (int tk = 0; tk < 4; ++tk){
      const int n = tok0 + wid*4 + tk;
      const int tl = n >> 4, nr = n & 15;
      if (lane < 48){
        const size_t idx = ((((size_t)bh*98 + tl)*5 + (lane>>4))*64
                           + ((lane&15)>>2)*16 + nr)*4 + (lane&3);
        ((u32*)Kt)[idx] = pack2(v0[tk], v1[tk]);
      } else {
        const int m = lane - 48;
        u32 pr_[2];
        #pragma unroll
        for (int h2 = 0; h2 < 2; ++h2){
          u32 w_ = 0;
          #pragma unroll
          for (int e = 0; e < 2; ++e){
            const int jj = 4*m + 2*h2 + e;
            bool on = (jj < 14) ? (jj == hh[tk]) : (jj < 28) ? (jj-14 == ww[tk])
                     : (jj < 36) ? (jj-28 == tt[tk]) : false;
            if (on) w_ |= (0x3F80u << (16*e));
          }
          pr_[h2] = w_;
        }
        const size_t bidx = ((((size_t)bh*98 + tl)*5 + (3 + (m>>3)))*64
                            + ((m&7)>>1)*16 + nr)*4 + 2*(m&1);
        *(uint2*)((u32*)Kt + bidx) = make_uint2(pr_[0], pr_[1]);
      }
    }
  } else {
    __syncthreads();                              // slab -> vres overlay
    #pragma unroll
    for (int tk = 0; tk < 4; ++tk){
      if (lane < 48) sm.vres[wid*4 + tk][lane] = pack2(v0[tk], v1[tk]);
    }
    __syncthreads();
    if (threadIdx.x < 2*HD_){
      const int grp = threadIdx.x / HD_, c = threadIdx.x % HD_;
      const int t0g = grp*8;
      u32 o[4];
      #pragma unroll
      for (int i = 0; i < 4; ++i){
        const u32 a = sm.vres[t0g + 2*i][c>>1], b = sm.vres[t0g + 2*i+1][c>>1];
        const u32 ra = (c&1) ? (a >> 16) : (a & 0xffffu);
        const u32 rb = (c&1) ? (b >> 16) : (b & 0xffffu);
        o[i] = ra | (rb << 16);
      }
      const int n0g = tok0 + t0g;
      const int pr = n0g >> 5, qd = (n0g & 31) >> 3;
      bf_t* dst = Vtt + ((((size_t)bh*49 + pr)*6 + (c>>4))*64 + qd*16 + (c&15))*8;
      *(uint4*)dst = make_uint4(o[0], o[1], o[2], o[3]);
    }
  }
}

// ---------------------------------------------------------------------------
// K4: MFMA flash attention, 8-wave in-block split-K, fragment-tiled K/V.
// R25 (verified): phase-A/phase-B combine epilogue -- per-row merge weights
// computed once, vectorized Os/qp reads, one uint2 coalesced store/thread.
// ---------------------------------------------------------------------------
__global__ __launch_bounds__(512) void k_attn(
    const bf_t* __restrict__ Qaug, const bf_t* __restrict__ Kt,
    const bf_t* __restrict__ Vtt, const bf_t* __restrict__ qp,
    bf_t* __restrict__ attb){
  __shared__ __align__(16) short Pb[8][16][40];   // per-wave P tile (+8 pad)
  __shared__ bf_t Os[8][16][96];                  // per-wave partial O (bf16)
  __shared__ float ms[8][16], ls[8][16];          // per-wave partial m, l
  __shared__ float wts[16][8];                    // merged per-row weights
  const int wid = threadIdx.x >> 6, lane = threadIdx.x & 63;
  const int bh = blockIdx.x / 98, qt = blockIdx.x % 98;
  const int q0 = qt*16;
  const int nl = lane & 15, quad = lane >> 4;

  bf16x8 qa[5];
  {
    const bf_t* Qrow = Qaug + ((size_t)bh*N_ + q0 + nl)*CAUG_ + quad*8;
    #pragma unroll
    for (int i = 0; i < 5; ++i) qa[i] = *(const bf16x8*)(Qrow + i*32);
  }
  short* Pw = &Pb[wid][0][0];

  f32x4 O[6];
  #pragma unroll
  for (int i = 0; i < 6; ++i) O[i] = (f32x4){0.f,0.f,0.f,0.f};
  float mc[4]   = {0.f,0.f,0.f,0.f};
  float rmax[4] = {-3e38f,-3e38f,-3e38f,-3e38f};
  float l[4]    = {0.f,0.f,0.f,0.f};

  auto s_tile = [&](int tl, int half){
    const bf_t* Kp = Kt + (((size_t)bh*98 + tl)*5*64 + lane)*8;
    f32x4 s = (f32x4){0.f,0.f,0.f,0.f};
    #pragma unroll
    for (int i = 0; i < 5; ++i)
      s = __builtin_amdgcn_mfma_f32_16x16x32_bf16(qa[i], *(const bf16x8*)(Kp + i*512), s, 0, 0, 0);
    #pragma unroll
    for (int r = 0; r < 4; ++r){
      rmax[r] = fmaxf(rmax[r], s[r]);
      const float p = exp2f(s[r] - mc[r]);
      l[r] += p;
      Pw[(quad*4 + r)*40 + half*16 + nl] = (short)f2b(p);
    }
  };
  auto rescale = [&](){
    #pragma unroll
    for (int r = 0; r < 4; ++r){
      float tm = rmax[r];
      tm = fmaxf(tm, __shfl_xor(tm, 1));
      tm = fmaxf(tm, __shfl_xor(tm, 2));
      tm = fmaxf(tm, __shfl_xor(tm, 4));
      tm = fmaxf(tm, __shfl_xor(tm, 8));
      const float mn = fmaxf(mc[r], tm);
      const float al = exp2f(mc[r] - mn);
      mc[r] = mn; l[r] *= al;
      #pragma unroll
      for (int ct = 0; ct < 6; ++ct) O[ct][r] *= al;
    }
  };

  const int p0 = (wid == 0) ? 0 : (7 + 6*(wid-1));
  const int npairs = (wid == 0) ? 7 : 6;
  #pragma unroll 1
  for (int pi = 0; pi < npairs; ++pi){
    const int kp = p0 + pi;
    s_tile(2*kp,     0);
    s_tile(2*kp + 1, 1);
    const bf16x8 pa = *(const bf16x8*)(Pw + nl*40 + quad*8);
    const bf_t* Vp = Vtt + (((size_t)bh*49 + kp)*6*64 + lane)*8;
    #pragma unroll
    for (int ct = 0; ct < 6; ++ct)
      O[ct] = __builtin_amdgcn_mfma_f32_16x16x32_bf16(pa, *(const bf16x8*)(Vp + ct*512), O[ct], 0, 0, 0);
    if (pi == npairs-1) rescale();
  }

  #pragma unroll
  for (int r = 0; r < 4; ++r){
    float ls_ = l[r];
    ls_ += __shfl_xor(ls_, 1); ls_ += __shfl_xor(ls_, 2);
    ls_ += __shfl_xor(ls_, 4); ls_ += __shfl_xor(ls_, 8);
    if (nl == 0){ ms[wid][quad*4 + r] = mc[r]; ls[wid][quad*4 + r] = ls_; }
    #pragma unroll
    for (int ct = 0; ct < 6; ++ct) Os[wid][quad*4 + r][ct*16 + nl] = f2b(O[ct][r]);
  }
  __syncthreads();

  // ---- phase A: per-row merge weights (once, folded with 1/L) ----
  if (threadIdx.x < 16){
    const int row = threadIdx.x;
    float mx = -3e38f;
    #pragma unroll
    for (int w = 0; w < 8; ++w) mx = fmaxf(mx, ms[w][row]);
    float wv[8]; float L = 0.f;
    #pragma unroll
    for (int w = 0; w < 8; ++w){
      wv[w] = exp2f(ms[w][row] - mx);
      L = fmaf(wv[w], ls[w][row], L);
    }
    const float rL = 1.f / L;
    #pragma unroll
    for (int w = 0; w < 8; ++w) wts[row][w] = wv[w]*rL;
  }
  __syncthreads();

  // ---- phase B: 384 threads x 4 cols, vectorized reads + uint2 store ----
  if (threadIdx.x < 384){
    const int row = threadIdx.x / 24, gg = threadIdx.x % 24;
    const int col0 = gg*4;
    float w8[8];
    #pragma unroll
    for (int w = 0; w < 8; ++w) w8[w] = wts[row][w];
    float a0 = 0.f, a1 = 0.f, a2 = 0.f, a3 = 0.f;
    #pragma unroll
    for (int w = 0; w < 8; ++w){
      const ushort4 o4 = *(const ushort4*)&Os[w][row][col0];
      a0 = fmaf(w8[w], b2f(o4.x), a0);
      a1 = fmaf(w8[w], b2f(o4.y), a1);
      a2 = fmaf(w8[w], b2f(o4.z), a2);
      a3 = fmaf(w8[w], b2f(o4.w), a3);
    }
    const ushort4 qv = *(const ushort4*)(qp + ((size_t)bh*N_ + q0 + row)*HD_ + col0);
    const u32 lo = pack2(a0 + b2f(qv.x), a1 + b2f(qv.y));
    const u32 hi = pack2(a2 + b2f(qv.z), a3 + b2f(qv.w));
    const int bb = bh >> 2, head = bh & 3;
    const int grow0 = bb*N_ + q0;                 // multiple of 16
    *(uint2*)(attb + ftidx(grow0 + row, head*HD_ + col0)) = make_uint2(lo, hi);
  }
}

// ---------------------------------------------------------------------------
// K5: output projection via MFMA, fragment-tiled A (attb) and B (Wpt).
// R26: per-wave row-tile halved 32->16. Grid (49,3) was 147 blocks =
// 0.57 blocks/CU (~43% of CUs idle); now (98,3) = 294 blocks, 1176 waves.
// ---------------------------------------------------------------------------
__global__ __launch_bounds__(256) void k_proj(const bf_t* __restrict__ At,
    const bf_t* __restrict__ Wpt, const float* __restrict__ pb,
    float* __restrict__ out){
  const int wid = threadIdx.x >> 6, lane = threadIdx.x & 63;
  const int wr = wid & 1, wc = wid >> 1;
  const int nl = lane & 15, quad = lane >> 4;
  const int r0 = blockIdx.x*32 + wr*16;
  const int mt0 = r0 >> 4;
  const int nt0 = blockIdx.y*8 + wc*4;
  f32x4 acc[4];
  #pragma unroll
  for (int j = 0; j < 4; ++j) acc[j] = (f32x4){0.f,0.f,0.f,0.f};
  const bf_t* A0 = At  + ((size_t)mt0*12*64 + lane)*8;
  const bf_t* B0 = Wpt + ((size_t)nt0*12*64 + lane)*8;
  #pragma unroll 2
  for (int k0 = 0; k0 < 12; ++k0){
    const bf16x8 a0 = *(const bf16x8*)(A0 + k0*512);
    bf16x8 bf[4];
    #pragma unroll
    for (int j = 0; j < 4; ++j) bf[j] = *(const bf16x8*)(B0 + (size_t)(j*12 + k0)*512);
    #pragma unroll
    for (int j = 0; j < 4; ++j)
      acc[j] = __builtin_amdgcn_mfma_f32_16x16x32_bf16(a0, bf[j], acc[j], 0, 0, 0);
  }
  #pragma unroll
  for (int r = 0; r < 4; ++r){
    const int m = r0 + quad*4 + r;
    #pragma unroll
    for (int j = 0; j < 4; ++j){
      const int col = (nt0 + j)*16 + nl;
      out[(size_t)m*DIM_ + col] = acc[j][r] + pb[col];
    }
  }
}

// ---------------------------------------------------------------------------
extern "C" void kernel_launch(void* const* d_in, const int* in_sizes, int n_in,
                              void* d_out, int out_size, void* d_ws, size_t ws_size,
                              hipStream_t stream){
  const float* x      = (const float*)d_in[0];
  const float* qkv_w  = (const float*)d_in[1];
  const float* proj_w = (const float*)d_in[2];
  const float* proj_b = (const float*)d_in[3];
  const float* pqw    = (const float*)d_in[4];
  const float* pkw    = (const float*)d_in[5];
  const float* pvw    = (const float*)d_in[6];
  const float* nqw    = (const float*)d_in[7];
  const float* nqb    = (const float*)d_in[8];
  const float* nkw    = (const float*)d_in[9];
  const float* nkb    = (const float*)d_in[10];
  const float* nvw    = (const float*)d_in[11];
  const float* nvb    = (const float*)d_in[12];
  const float* rph    = (const float*)d_in[13];
  const float* rpw    = (const float*)d_in[14];
  const float* rpt    = (const float*)d_in[15];

  // Workspace (bytes), ~23.7 MB total. attb overlays raw_q after pooling.
  char* p = (char*)d_ws;
  const size_t RAW = (size_t)BH_*N_*HD_*2;       // 2,408,448 B
  const size_t AUG = (size_t)BH_*N_*CAUG_*2;     // 4,014,080 B
  bf_t* xb     = (bf_t*)(p);                     // frag-tiled
  bf_t* wqkvb  = (bf_t*)(p + RAW);               // frag-tiled
  bf_t* wprojb = (bf_t*)(p + RAW + 884736);      // frag-tiled
  char* p2 = p + RAW + 884736 + 294912;
  bf_t* raw_q  = (bf_t*)(p2);
  bf_t* raw_k  = (bf_t*)(p2 + RAW);
  bf_t* raw_v  = (bf_t*)(p2 + 2*RAW);
  bf_t* attb   = raw_q;                          // overlays raw_q (frag-tiled)
  bf_t* qp     = (bf_t*)(p2 + 3*RAW);
  bf_t* Qaug   = (bf_t*)(p2 + 4*RAW);
  bf_t* Kt     = (bf_t*)(p2 + 4*RAW + AUG);      // tiled Kaug
  bf_t* Vtt    = (bf_t*)(p2 + 4*RAW + 2*AUG);    // tiled V
  float* wtq   = (float*)(p2 + 4*RAW + 2*AUG + RAW);   // 3 x 27x96 fp32
  float* wtk   = wtq + 27*HD_;
  float* wtv   = wtk + 27*HD_;

  k_cast     <<<CAST_MBLOCKS + 31, 256, 0, stream>>>(x, xb, qkv_w, wqkvb, proj_w, wprojb,
                                                     pqw, pkw, pvw, wtq, wtk, wtv);
  k_qkv      <<<dim3(BN_/32, 9),  256, 0, stream>>>(xb, wqkvb, raw_q, raw_k, raw_v);
  k_pool_slab<<<3*784,            256, 0, stream>>>(raw_q, raw_k, raw_v,
                                                    wtq, wtk, wtv,
                                                    nqw, nqb, nkw, nkb, nvw, nvb,
                                                    rph, rpw, rpt,
                                                    qp, Qaug, Kt, Vtt);
  k_attn     <<<BH_*98,           512, 0, stream>>>(Qaug, Kt, Vtt, qp, attb);
  k_proj     <<<dim3(BN_/32, 3),  256, 0, stream>>>(attb, wprojb, proj_b, (float*)d_out);
}

// Round 15
// 189.262 us; speedup vs baseline: 1.0029x; 1.0029x over previous
//
#include <hip/hip_runtime.h>

// Problem constants (fixed by reference)
#define B_    2
#define NH_   4
#define T_    8
#define H_    14
#define W_    14
#define HW_   196             // H*W
#define HD_   96
#define DIM_  384
#define N_    1568            // T*H*W
#define BH_   (B_*NH_)        // 8
#define BN_   (B_*N_)         // 3136
#define BHN_  (BH_*N_)        // 12544
#define CAUG_ 160             // 96 + 36 one-hot/bias + 28 pad

typedef unsigned short bf_t;
typedef unsigned int   u32;
typedef __attribute__((ext_vector_type(8))) short bf16x8;
typedef __attribute__((ext_vector_type(4))) float f32x4;

#define LOG2E 1.4426950408889634f
#define QSCALE_LOG2E 0.14724445f   /* 96^-0.5 * log2(e) */

static __device__ __forceinline__ float lo16(u32 v){ union{u32 i; float f;}x; x.i = v<<16;           return x.f; }
static __device__ __forceinline__ float hi16(u32 v){ union{u32 i; float f;}x; x.i = v & 0xffff0000u; return x.f; }
static __device__ __forceinline__ float b2f(bf_t v){ union{u32 i; float f;}x; x.i = ((u32)v)<<16;    return x.f; }
static __device__ __forceinline__ bf_t  f2b(float f){
  union{float f; u32 i;} x; x.f = f;
  return (bf_t)((x.i + 0x7fffu + ((x.i>>16)&1u)) >> 16);   // RNE
}
static __device__ __forceinline__ u32 pack2(float a, float b){
  return (u32)f2b(a) | ((u32)f2b(b) << 16);
}
// fragment-tile index for a row-major [R][384] matrix element (row, k)
static __device__ __forceinline__ size_t ftidx(int row, int k){
  return ((((size_t)(row>>4))*12 + (k>>5))*64 + ((k>>3)&3)*16 + (row&15))*8 + (k&7);
}

// ---------------------------------------------------------------------------
// K0: cast x / qkv_w / proj_w fp32 -> bf16 in FRAGMENT-TILED layout, plus
// conv-weight transpose [96][27]->[27][96] fp32 (last 31 blocks).
// R24 (verified -2.8us): tile-per-wave; one wave owns one 16x32 fragment
// tile -> lane l writes 16B contiguous, wave writes a coalesced 1KB tile.
// ---------------------------------------------------------------------------
#define NA_ (BN_*DIM_)        // 1,204,224
#define NB_ (3*DIM_*DIM_)     //   442,368
#define NC_ (DIM_*DIM_)       //   147,456
#define TILES_X 2352          // (3136/16)*(384/32)
#define TILES_B 864           // (1152/16)*12
#define TILES_C 288           // (384/16)*12
#define CAST_MBLOCKS ((TILES_X+TILES_B+TILES_C)/4)   // 876 exactly

__global__ __launch_bounds__(256) void k_cast(
    const float* __restrict__ a, bf_t* __restrict__ ad,
    const float* __restrict__ b, bf_t* __restrict__ bd,
    const float* __restrict__ c, bf_t* __restrict__ cd,
    const float* __restrict__ wq, const float* __restrict__ wk,
    const float* __restrict__ wv, float* __restrict__ tq,
    float* __restrict__ tk, float* __restrict__ tv){
  if (blockIdx.x < CAST_MBLOCKS){
    const int tile = blockIdx.x*4 + (threadIdx.x >> 6);
    const int lane = threadIdx.x & 63;
    const float* src; bf_t* dst; int tl;
    if (tile < TILES_X)                { src = a; dst = ad; tl = tile; }
    else if (tile < TILES_X + TILES_B) { src = b; dst = bd; tl = tile - TILES_X; }
    else                               { src = c; dst = cd; tl = tile - TILES_X - TILES_B; }
    const int mt = tl / 12, kt = tl % 12;
    const int row = mt*16 + (lane & 15);
    const int k0  = kt*32 + (lane >> 4)*8;
    const float4 v0 = *(const float4*)(src + (size_t)row*DIM_ + k0);
    const float4 v1 = *(const float4*)(src + (size_t)row*DIM_ + k0 + 4);
    const u32 w0 = pack2(v0.x, v0.y), w1 = pack2(v0.z, v0.w);
    const u32 w2 = pack2(v1.x, v1.y), w3 = pack2(v1.z, v1.w);
    *(uint4*)(dst + (size_t)tl*512 + lane*8) = make_uint4(w0, w1, w2, w3);
  } else {
    const int idx = (blockIdx.x - CAST_MBLOCKS)*256 + threadIdx.x;
    if (idx >= 3*HD_*27) return;
    const int t = idx / (HD_*27), rem = idx % (HD_*27);
    const int ch = rem / 27, j = rem % 27;
    const float* s = (t==0)? wq : (t==1)? wk : wv;
    float* d       = (t==0)? tq : (t==1)? tk : tv;
    d[j*HD_ + ch] = s[ch*27 + j];
  }
}

// ---------------------------------------------------------------------------
// K1: QKV GEMM via MFMA, fragment-tiled operands.
// R27 = R25 form: 32-row tile per wave RESTORED. R26's 16-row split
// measured +5.6us (pool-adjusted) -- B-reuse halving doubled B-fragment
// loads + epilogue work; GEMMs are issue/L2-BW-bound, not latency-bound.
// ---------------------------------------------------------------------------
__global__ __launch_bounds__(256) void k_qkv(const bf_t* __restrict__ Xt,
    const bf_t* __restrict__ Wt,
    bf_t* __restrict__ q, bf_t* __restrict__ k, bf_t* __restrict__ v){
  const int wid = threadIdx.x >> 6, lane = threadIdx.x & 63;
  const int wr = wid & 1, wc = wid >> 1;
  const int nl = lane & 15, quad = lane >> 4;
  const int r0 = blockIdx.x*64 + wr*32;
  const int mt0 = r0 >> 4;
  const int nt0 = blockIdx.y*8 + wc*4;
  f32x4 acc[2][4];
  #pragma unroll
  for (int i = 0; i < 2; ++i)
    #pragma unroll
    for (int j = 0; j < 4; ++j) acc[i][j] = (f32x4){0.f,0.f,0.f,0.f};
  const bf_t* A0 = Xt + ((size_t)mt0*12*64 + lane)*8;
  const bf_t* B0 = Wt + ((size_t)nt0*12*64 + lane)*8;
  #pragma unroll 2
  for (int k0 = 0; k0 < 12; ++k0){
    const bf16x8 a0 = *(const bf16x8*)(A0 + k0*512);
    const bf16x8 a1 = *(const bf16x8*)(A0 + 12*512 + k0*512);
    bf16x8 bf[4];
    #pragma unroll
    for (int j = 0; j < 4; ++j) bf[j] = *(const bf16x8*)(B0 + (size_t)(j*12 + k0)*512);
    #pragma unroll
    for (int j = 0; j < 4; ++j){
      acc[0][j] = __builtin_amdgcn_mfma_f32_16x16x32_bf16(a0, bf[j], acc[0][j], 0, 0, 0);
      acc[1][j] = __builtin_amdgcn_mfma_f32_16x16x32_bf16(a1, bf[j], acc[1][j], 0, 0, 0);
    }
  }
  #pragma unroll
  for (int i = 0; i < 2; ++i){
    #pragma unroll
    for (int r = 0; r < 4; ++r){
      const int m  = r0 + i*16 + quad*4 + r;
      const int bb = m / N_, nn = m % N_;
      #pragma unroll
      for (int j = 0; j < 4; ++j){
        const int col = (nt0 + j)*16 + nl;
        const int s = col / DIM_, rem = col - s*DIM_;
        const int head = rem / HD_, hc = rem % HD_;
        bf_t* dst = (s==0) ? q : (s==1) ? k : v;
        dst[((size_t)(bb*NH_ + head)*N_ + nn)*HD_ + hc] = f2b(acc[i][j][r]);
      }
    }
  }
}

static __device__ __forceinline__ void ln_butterfly(
    float v0, float v1, float& mean, float& rstd){
  float s  = v0 + v1;
  float s2 = v0*v0 + v1*v1;
  #pragma unroll
  for (int off = 32; off > 0; off >>= 1){
    s  += __shfl_xor(s,  off);
    s2 += __shfl_xor(s2, off);
  }
  mean = s * (1.f/HD_);
  const float var = fmaxf(s2*(1.f/HD_) - mean*mean, 0.f);
  rstd = rsqrtf(var + 1e-6f);
}

// ---------------------------------------------------------------------------
// K2: LDS-slab pooled conv+LN, 16 tokens/block (4 waves x 4 tokens).
// Halo slab 162 rows (3t x 3h x 18w) x 96ch bf16 = 31.1 KB.
// R16 form (best measured). Ledger: R14 forced-occupancy spill (-),
// R17 deep pipeline (-), R19 XCD pinning (FETCH 22->3.9MB, timing-neutral).
// Observed env variance on identical code: 47.6-55.8us.
// ---------------------------------------------------------------------------
union PoolSM {
  bf_t  slab[162][HD_];       // 31,104 B  (phase 1)
  float qtmp[4][4][HD_];      //  6,144 B  (phase 2, sec 0; per-wave)
  u32   vres[16][48];         //  3,072 B  (phase 2, sec 2)
};

__global__ __launch_bounds__(256) void k_pool_slab(
    const bf_t* __restrict__ qr_, const bf_t* __restrict__ kr_, const bf_t* __restrict__ vr_,
    const float* __restrict__ wtq, const float* __restrict__ wtk, const float* __restrict__ wtv,
    const float* __restrict__ gq, const float* __restrict__ bq,
    const float* __restrict__ gk, const float* __restrict__ bk,
    const float* __restrict__ gv, const float* __restrict__ bv,
    const float* __restrict__ rph, const float* __restrict__ rpw,
    const float* __restrict__ rpt,
    bf_t* __restrict__ qp, bf_t* __restrict__ Qaug,
    bf_t* __restrict__ Kt, bf_t* __restrict__ Vtt){
  __shared__ __align__(16) PoolSM sm;
  const int wid = threadIdx.x >> 6, lane = threadIdx.x & 63;
  const int sec = blockIdx.x / 784;
  const int rr_ = blockIdx.x % 784;
  const int bh = rr_ / 98, tok0 = (rr_ % 98)*16;
  const bf_t*  src = (sec==0)? qr_ : (sec==1)? kr_ : vr_;
  const float* wt  = (sec==0)? wtq : (sec==1)? wtk : wtv;
  const float* g   = (sec==0)? gq  : (sec==1)? gk  : gv;
  const float* be  = (sec==0)? bq  : (sec==1)? bk  : bv;
  const bf_t* base = src + (size_t)bh*N_*HD_;

  // per-lane channel pair; first weight trio + LN params overlap staging
  const int c0 = (lane < 48) ? 2*lane : 0;
  float2 wcur[3], wnxt[3];
  #pragma unroll
  for (int dw = 0; dw < 3; ++dw) wcur[dw] = *(const float2*)(wt + dw*HD_ + c0);
  const float gg0 = g[c0], gg1 = g[c0+1], be0 = be[c0], be1 = be[c0+1];

  // ---- staging: batched loads into regs, then LDS writes (vmcnt pipeline) --
  {
    uint4 stg[8];
    #pragma unroll
    for (int it = 0; it < 8; ++it){
      const int li = threadIdx.x + it*256;
      const int lc = (li < 162*12) ? li : (162*12 - 1);
      const int rw = lc / 12, ss = lc % 12;
      const int aa = rw/54, bb2 = (rw%54)/18, cc = rw%18;
      int nn = tok0 + (aa-1)*HW_ + (bb2-1)*W_ + (cc-1);
      nn = min(max(nn, 0), N_-1);
      stg[it] = *(const uint4*)(base + (size_t)nn*HD_ + ss*8);
    }
    #pragma unroll
    for (int it = 0; it < 8; ++it){
      const int li = threadIdx.x + it*256;
      if (li < 162*12){
        const int rw = li / 12, ss = li % 12;
        *(uint4*)&sm.slab[rw][ss*8] = stg[it];
      }
    }
  }
  __syncthreads();

  // token coordinates (wave-uniform) + 27-bit validity masks
  int tt[4], hh[4], ww[4];
  u32 mr[4];
  #pragma unroll
  for (int tk = 0; tk < 4; ++tk){
    const int n = tok0 + wid*4 + tk;
    tt[tk] = n / HW_;
    const int rm = n % HW_;
    hh[tk] = rm / W_; ww[tk] = rm % W_;
    const u32 wb = (ww[tk] > 0 ? 1u : 0u) | 2u | (ww[tk] < W_-1 ? 4u : 0u);
    const u32 h9 = (hh[tk] > 0 ? wb : 0u) | (wb << 3) | (hh[tk] < H_-1 ? (wb << 6) : 0u);
    mr[tk] = (tt[tk] > 0 ? h9 : 0u) | (h9 << 9) | (tt[tk] < T_-1 ? (h9 << 18) : 0u);
  }

  // ---- phase 1: conv, software-pipelined row reads ----
  float v0[4] = {0.f,0.f,0.f,0.f}, v1[4] = {0.f,0.f,0.f,0.f};
  u32 rr[6], rrn[6];
  #pragma unroll
  for (int s = 0; s < 6; ++s) rr[s] = *(const u32*)&sm.slab[wid*4 + s][c0];
  #pragma unroll 1
  for (int j9 = 0; j9 < 9; ++j9){
    if (j9 < 8){
      const int jn = j9 + 1;
      const int rbn = (jn/3)*54 + (jn%3)*18 + wid*4;
      #pragma unroll
      for (int s = 0; s < 6; ++s) rrn[s] = *(const u32*)&sm.slab[rbn + s][c0];
      #pragma unroll
      for (int dw = 0; dw < 3; ++dw)
        wnxt[dw] = *(const float2*)(wt + (jn*3 + dw)*HD_ + c0);
    }
    #pragma unroll
    for (int tk = 0; tk < 4; ++tk){
      #pragma unroll
      for (int dw = 0; dw < 3; ++dw){
        const u32 d = (mr[tk] & (1u << dw)) ? rr[tk+dw] : 0u;
        v0[tk] = fmaf(wcur[dw].x, lo16(d), v0[tk]);
        v1[tk] = fmaf(wcur[dw].y, hi16(d), v1[tk]);
      }
      mr[tk] >>= 3;
    }
    #pragma unroll
    for (int s = 0; s < 6; ++s) rr[s] = rrn[s];
    #pragma unroll
    for (int dw = 0; dw < 3; ++dw) wcur[dw] = wnxt[dw];
  }
  // LayerNorm per token (results stay in v0/v1)
  #pragma unroll
  for (int tk = 0; tk < 4; ++tk){
    float a = v0[tk], b = v1[tk];
    if (lane >= 48){ a = 0.f; b = 0.f; }
    float mean, rstd;
    ln_butterfly(a, b, mean, rstd);
    v0[tk] = (a - mean)*rstd*gg0 + be0;
    v1[tk] = (b - mean)*rstd*gg1 + be1;
  }

  // ---- phase 2: outputs (qtmp/vres overlay slab; barrier before overlay) --
  if (sec == 0){
    __syncthreads();                              // slab -> qtmp overlay
    #pragma unroll
    for (int tk = 0; tk < 4; ++tk){
      const int n = tok0 + wid*4 + tk;
      const int token = bh*N_ + n;
      if (lane < 48){
        ((u32*)qp)  [(size_t)token*48 + lane] = pack2(v0[tk], v1[tk]);
        ((u32*)Qaug)[(size_t)token*80 + lane] = pack2(v0[tk]*QSCALE_LOG2E, v1[tk]*QSCALE_LOG2E);
        *(float2*)&sm.qtmp[wid][tk][c0] = make_float2(v0[tk], v1[tk]);
      }
    }
    // qtmp written/read by the SAME wave -> ordered by lgkmcnt, no barrier
    #pragma unroll
    for (int tk = 0; tk < 4; ++tk){
      const int n = tok0 + wid*4 + tk;
      const int token = bh*N_ + n;
      if (lane < 36){
        const float* tb; int idx;
        if (lane < 14)      { tb = rph; idx = hh[tk] - lane      + 13; }
        else if (lane < 28) { tb = rpw; idx = ww[tk] - (lane-14) + 13; }
        else                { tb = rpt; idx = tt[tk] - (lane-28) +  7; }
        const float4* t4 = (const float4*)(tb + (size_t)idx*HD_);
        const float4* q4 = (const float4*)&sm.qtmp[wid][tk][0];
        float ap[4] = {0.f, 0.f, 0.f, 0.f};
        #pragma unroll
        for (int i = 0; i < 24; ++i){
          const float4 rv = t4[i];
          const float4 qv = q4[i];                 // ds_read_b128 broadcast
          ap[i & 3] = fmaf(qv.x, rv.x,
                      fmaf(qv.y, rv.y,
                      fmaf(qv.z, rv.z,
                      fmaf(qv.w, rv.w, ap[i & 3]))));
        }
        const float acc = (ap[0] + ap[1]) + (ap[2] + ap[3]);
        Qaug[(size_t)token*CAUG_ + HD_ + lane] = f2b(acc * LOG2E);
      } else {
        Qaug[(size_t)token*CAUG_ + HD_ + lane] = 0;
      }
    }
  } else if (sec == 1){
    // no LDS use in this branch -> no barrier needed
    #pragma unroll
    for (int tk = 0; tk < 4; ++tk){
      const int n = tok0 + wid*4 + tk;
      const int tl = n >> 4, nr = n & 15;
      if (lane < 48){
        const size_t idx = ((((size_t)bh*98 + tl)*5 + (lane>>4))*64
                           + ((lane&15)>>2)*16 + nr)*4 + (lane&3);
        ((u32*)Kt)[idx] = pack2(v0[tk], v1[tk]);
      } else {
        const int m = lane - 48;
        u32 pr_[2];
        #pragma unroll
        for (int h2 = 0; h2 < 2; ++h2){
          u32 w_ = 0;
          #pragma unroll
          for (int e = 0; e < 2; ++e){
            const int jj = 4*m + 2*h2 + e;
            bool on = (jj < 14) ? (jj == hh[tk]) : (jj < 28) ? (jj-14 == ww[tk])
                     : (jj < 36) ? (jj-28 == tt[tk]) : false;
            if (on) w_ |= (0x3F80u << (16*e));
          }
          pr_[h2] = w_;
        }
        const size_t bidx = ((((size_t)bh*98 + tl)*5 + (3 + (m>>3)))*64
                            + ((m&7)>>1)*16 + nr)*4 + 2*(m&1);
        *(uint2*)((u32*)Kt + bidx) = make_uint2(pr_[0], pr_[1]);
      }
    }
  } else {
    __syncthreads();                              // slab -> vres overlay
    #pragma unroll
    for (int tk = 0; tk < 4; ++tk){
      if (lane < 48) sm.vres[wid*4 + tk][lane] = pack2(v0[tk], v1[tk]);
    }
    __syncthreads();
    if (threadIdx.x < 2*HD_){
      const int grp = threadIdx.x / HD_, c = threadIdx.x % HD_;
      const int t0g = grp*8;
      u32 o[4];
      #pragma unroll
      for (int i = 0; i < 4; ++i){
        const u32 a = sm.vres[t0g + 2*i][c>>1], b = sm.vres[t0g + 2*i+1][c>>1];
        const u32 ra = (c&1) ? (a >> 16) : (a & 0xffffu);
        const u32 rb = (c&1) ? (b >> 16) : (b & 0xffffu);
        o[i] = ra | (rb << 16);
      }
      const int n0g = tok0 + t0g;
      const int pr = n0g >> 5, qd = (n0g & 31) >> 3;
      bf_t* dst = Vtt + ((((size_t)bh*49 + pr)*6 + (c>>4))*64 + qd*16 + (c&15))*8;
      *(uint4*)dst = make_uint4(o[0], o[1], o[2], o[3]);
    }
  }
}

// ---------------------------------------------------------------------------
// K4: MFMA flash attention, 8-wave in-block split-K, fragment-tiled K/V.
// R25 (verified): phase-A/phase-B combine epilogue -- per-row merge weights
// computed once, vectorized Os/qp reads, one uint2 coalesced store/thread.
// ---------------------------------------------------------------------------
__global__ __launch_bounds__(512) void k_attn(
    const bf_t* __restrict__ Qaug, const bf_t* __restrict__ Kt,
    const bf_t* __restrict__ Vtt, const bf_t* __restrict__ qp,
    bf_t* __restrict__ attb){
  __shared__ __align__(16) short Pb[8][16][40];   // per-wave P tile (+8 pad)
  __shared__ bf_t Os[8][16][96];                  // per-wave partial O (bf16)
  __shared__ float ms[8][16], ls[8][16];          // per-wave partial m, l
  __shared__ float wts[16][8];                    // merged per-row weights
  const int wid = threadIdx.x >> 6, lane = threadIdx.x & 63;
  const int bh = blockIdx.x / 98, qt = blockIdx.x % 98;
  const int q0 = qt*16;
  const int nl = lane & 15, quad = lane >> 4;

  bf16x8 qa[5];
  {
    const bf_t* Qrow = Qaug + ((size_t)bh*N_ + q0 + nl)*CAUG_ + quad*8;
    #pragma unroll
    for (int i = 0; i < 5; ++i) qa[i] = *(const bf16x8*)(Qrow + i*32);
  }
  short* Pw = &Pb[wid][0][0];

  f32x4 O[6];
  #pragma unroll
  for (int i = 0; i < 6; ++i) O[i] = (f32x4){0.f,0.f,0.f,0.f};
  float mc[4]   = {0.f,0.f,0.f,0.f};
  float rmax[4] = {-3e38f,-3e38f,-3e38f,-3e38f};
  float l[4]    = {0.f,0.f,0.f,0.f};

  auto s_tile = [&](int tl, int half){
    const bf_t* Kp = Kt + (((size_t)bh*98 + tl)*5*64 + lane)*8;
    f32x4 s = (f32x4){0.f,0.f,0.f,0.f};
    #pragma unroll
    for (int i = 0; i < 5; ++i)
      s = __builtin_amdgcn_mfma_f32_16x16x32_bf16(qa[i], *(const bf16x8*)(Kp + i*512), s, 0, 0, 0);
    #pragma unroll
    for (int r = 0; r < 4; ++r){
      rmax[r] = fmaxf(rmax[r], s[r]);
      const float p = exp2f(s[r] - mc[r]);
      l[r] += p;
      Pw[(quad*4 + r)*40 + half*16 + nl] = (short)f2b(p);
    }
  };
  auto rescale = [&](){
    #pragma unroll
    for (int r = 0; r < 4; ++r){
      float tm = rmax[r];
      tm = fmaxf(tm, __shfl_xor(tm, 1));
      tm = fmaxf(tm, __shfl_xor(tm, 2));
      tm = fmaxf(tm, __shfl_xor(tm, 4));
      tm = fmaxf(tm, __shfl_xor(tm, 8));
      const float mn = fmaxf(mc[r], tm);
      const float al = exp2f(mc[r] - mn);
      mc[r] = mn; l[r] *= al;
      #pragma unroll
      for (int ct = 0; ct < 6; ++ct) O[ct][r] *= al;
    }
  };

  const int p0 = (wid == 0) ? 0 : (7 + 6*(wid-1));
  const int npairs = (wid == 0) ? 7 : 6;
  #pragma unroll 1
  for (int pi = 0; pi < npairs; ++pi){
    const int kp = p0 + pi;
    s_tile(2*kp,     0);
    s_tile(2*kp + 1, 1);
    const bf16x8 pa = *(const bf16x8*)(Pw + nl*40 + quad*8);
    const bf_t* Vp = Vtt + (((size_t)bh*49 + kp)*6*64 + lane)*8;
    #pragma unroll
    for (int ct = 0; ct < 6; ++ct)
      O[ct] = __builtin_amdgcn_mfma_f32_16x16x32_bf16(pa, *(const bf16x8*)(Vp + ct*512), O[ct], 0, 0, 0);
    if (pi == npairs-1) rescale();
  }

  #pragma unroll
  for (int r = 0; r < 4; ++r){
    float ls_ = l[r];
    ls_ += __shfl_xor(ls_, 1); ls_ += __shfl_xor(ls_, 2);
    ls_ += __shfl_xor(ls_, 4); ls_ += __shfl_xor(ls_, 8);
    if (nl == 0){ ms[wid][quad*4 + r] = mc[r]; ls[wid][quad*4 + r] = ls_; }
    #pragma unroll
    for (int ct = 0; ct < 6; ++ct) Os[wid][quad*4 + r][ct*16 + nl] = f2b(O[ct][r]);
  }
  __syncthreads();

  // ---- phase A: per-row merge weights (once, folded with 1/L) ----
  if (threadIdx.x < 16){
    const int row = threadIdx.x;
    float mx = -3e38f;
    #pragma unroll
    for (int w = 0; w < 8; ++w) mx = fmaxf(mx, ms[w][row]);
    float wv[8]; float L = 0.f;
    #pragma unroll
    for (int w = 0; w < 8; ++w){
      wv[w] = exp2f(ms[w][row] - mx);
      L = fmaf(wv[w], ls[w][row], L);
    }
    const float rL = 1.f / L;
    #pragma unroll
    for (int w = 0; w < 8; ++w) wts[row][w] = wv[w]*rL;
  }
  __syncthreads();

  // ---- phase B: 384 threads x 4 cols, vectorized reads + uint2 store ----
  if (threadIdx.x < 384){
    const int row = threadIdx.x / 24, gg = threadIdx.x % 24;
    const int col0 = gg*4;
    float w8[8];
    #pragma unroll
    for (int w = 0; w < 8; ++w) w8[w] = wts[row][w];
    float a0 = 0.f, a1 = 0.f, a2 = 0.f, a3 = 0.f;
    #pragma unroll
    for (int w = 0; w < 8; ++w){
      const ushort4 o4 = *(const ushort4*)&Os[w][row][col0];
      a0 = fmaf(w8[w], b2f(o4.x), a0);
      a1 = fmaf(w8[w], b2f(o4.y), a1);
      a2 = fmaf(w8[w], b2f(o4.z), a2);
      a3 = fmaf(w8[w], b2f(o4.w), a3);
    }
    const ushort4 qv = *(const ushort4*)(qp + ((size_t)bh*N_ + q0 + row)*HD_ + col0);
    const u32 lo = pack2(a0 + b2f(qv.x), a1 + b2f(qv.y));
    const u32 hi = pack2(a2 + b2f(qv.z), a3 + b2f(qv.w));
    const int bb = bh >> 2, head = bh & 3;
    const int grow0 = bb*N_ + q0;                 // multiple of 16
    *(uint2*)(attb + ftidx(grow0 + row, head*HD_ + col0)) = make_uint2(lo, hi);
  }
}

// ---------------------------------------------------------------------------
// K5: output projection via MFMA, fragment-tiled A (attb) and B (Wpt).
// R27 = R25 form: 32-row tile per wave restored (R26's 16-row split
// regressed; see k_qkv note).
// ---------------------------------------------------------------------------
__global__ __launch_bounds__(256) void k_proj(const bf_t* __restrict__ At,
    const bf_t* __restrict__ Wpt, const float* __restrict__ pb,
    float* __restrict__ out){
  const int wid = threadIdx.x >> 6, lane = threadIdx.x & 63;
  const int wr = wid & 1, wc = wid >> 1;
  const int nl = lane & 15, quad = lane >> 4;
  const int r0 = blockIdx.x*64 + wr*32;
  const int mt0 = r0 >> 4;
  const int nt0 = blockIdx.y*8 + wc*4;
  f32x4 acc[2][4];
  #pragma unroll
  for (int i = 0; i < 2; ++i)
    #pragma unroll
    for (int j = 0; j < 4; ++j) acc[i][j] = (f32x4){0.f,0.f,0.f,0.f};
  const bf_t* A0 = At  + ((size_t)mt0*12*64 + lane)*8;
  const bf_t* B0 = Wpt + ((size_t)nt0*12*64 + lane)*8;
  #pragma unroll 2
  for (int k0 = 0; k0 < 12; ++k0){
    const bf16x8 a0 = *(const bf16x8*)(A0 + k0*512);
    const bf16x8 a1 = *(const bf16x8*)(A0 + 12*512 + k0*512);
    bf16x8 bf[4];
    #pragma unroll
    for (int j = 0; j < 4; ++j) bf[j] = *(const bf16x8*)(B0 + (size_t)(j*12 + k0)*512);
    #pragma unroll
    for (int j = 0; j < 4; ++j){
      acc[0][j] = __builtin_amdgcn_mfma_f32_16x16x32_bf16(a0, bf[j], acc[0][j], 0, 0, 0);
      acc[1][j] = __builtin_amdgcn_mfma_f32_16x16x32_bf16(a1, bf[j], acc[1][j], 0, 0, 0);
    }
  }
  #pragma unroll
  for (int i = 0; i < 2; ++i){
    #pragma unroll
    for (int r = 0; r < 4; ++r){
      const int m = r0 + i*16 + quad*4 + r;
      #pragma unroll
      for (int j = 0; j < 4; ++j){
        const int col = (nt0 + j)*16 + nl;
        out[(size_t)m*DIM_ + col] = acc[i][j][r] + pb[col];
      }
    }
  }
}

// ---------------------------------------------------------------------------
extern "C" void kernel_launch(void* const* d_in, const int* in_sizes, int n_in,
                              void* d_out, int out_size, void* d_ws, size_t ws_size,
                              hipStream_t stream){
  const float* x      = (const float*)d_in[0];
  const float* qkv_w  = (const float*)d_in[1];
  const float* proj_w = (const float*)d_in[2];
  const float* proj_b = (const float*)d_in[3];
  const float* pqw    = (const float*)d_in[4];
  const float* pkw    = (const float*)d_in[5];
  const float* pvw    = (const float*)d_in[6];
  const float* nqw    = (const float*)d_in[7];
  const float* nqb    = (const float*)d_in[8];
  const float* nkw    = (const float*)d_in[9];
  const float* nkb    = (const float*)d_in[10];
  const float* nvw    = (const float*)d_in[11];
  const float* nvb    = (const float*)d_in[12];
  const float* rph    = (const float*)d_in[13];
  const float* rpw    = (const float*)d_in[14];
  const float* rpt    = (const float*)d_in[15];

  // Workspace (bytes), ~23.7 MB total. attb overlays raw_q after pooling.
  char* p = (char*)d_ws;
  const size_t RAW = (size_t)BH_*N_*HD_*2;       // 2,408,448 B
  const size_t AUG = (size_t)BH_*N_*CAUG_*2;     // 4,014,080 B
  bf_t* xb     = (bf_t*)(p);                     // frag-tiled
  bf_t* wqkvb  = (bf_t*)(p + RAW);               // frag-tiled
  bf_t* wprojb = (bf_t*)(p + RAW + 884736);      // frag-tiled
  char* p2 = p + RAW + 884736 + 294912;
  bf_t* raw_q  = (bf_t*)(p2);
  bf_t* raw_k  = (bf_t*)(p2 + RAW);
  bf_t* raw_v  = (bf_t*)(p2 + 2*RAW);
  bf_t* attb   = raw_q;                          // overlays raw_q (frag-tiled)
  bf_t* qp     = (bf_t*)(p2 + 3*RAW);
  bf_t* Qaug   = (bf_t*)(p2 + 4*RAW);
  bf_t* Kt     = (bf_t*)(p2 + 4*RAW + AUG);      // tiled Kaug
  bf_t* Vtt    = (bf_t*)(p2 + 4*RAW + 2*AUG);    // tiled V
  float* wtq   = (float*)(p2 + 4*RAW + 2*AUG + RAW);   // 3 x 27x96 fp32
  float* wtk   = wtq + 27*HD_;
  float* wtv   = wtk + 27*HD_;

  k_cast     <<<CAST_MBLOCKS + 31, 256, 0, stream>>>(x, xb, qkv_w, wqkvb, proj_w, wprojb,
                                                     pqw, pkw, pvw, wtq, wtk, wtv);
  k_qkv      <<<dim3(BN_/64, 9),  256, 0, stream>>>(xb, wqkvb, raw_q, raw_k, raw_v);
  k_pool_slab<<<3*784,            256, 0, stream>>>(raw_q, raw_k, raw_v,
                                                    wtq, wtk, wtv,
                                                    nqw, nqb, nkw, nkb, nvw, nvb,
                                                    rph, rpw, rpt,
                                                    qp, Qaug, Kt, Vtt);
  k_attn     <<<BH_*98,           512, 0, stream>>>(Qaug, Kt, Vtt, qp, attb);
  k_proj     <<<dim3(BN_/64, 3),  256, 0, stream>>>(attb, wprojb, proj_b, (float*)d_out);
}

// Round 16
// 187.054 us; speedup vs baseline: 1.0147x; 1.0118x over previous
//
#include <hip/hip_runtime.h>

// Problem constants (fixed by reference)
#define B_    2
#define NH_   4
#define T_    8
#define H_    14
#define W_    14
#define HW_   196             // H*W
#define HD_   96
#define DIM_  384
#define N_    1568            // T*H*W
#define BH_   (B_*NH_)        // 8
#define BN_   (B_*N_)         // 3136
#define BHN_  (BH_*N_)        // 12544
#define CAUG_ 160             // 96 + 36 one-hot/bias + 28 pad

typedef unsigned short bf_t;
typedef unsigned int   u32;
typedef __attribute__((ext_vector_type(8))) short bf16x8;
typedef __attribute__((ext_vector_type(4))) float f32x4;

#define LOG2E 1.4426950408889634f
#define QSCALE_LOG2E 0.14724445f   /* 96^-0.5 * log2(e) */

static __device__ __forceinline__ float lo16(u32 v){ union{u32 i; float f;}x; x.i = v<<16;           return x.f; }
static __device__ __forceinline__ float hi16(u32 v){ union{u32 i; float f;}x; x.i = v & 0xffff0000u; return x.f; }
static __device__ __forceinline__ float b2f(bf_t v){ union{u32 i; float f;}x; x.i = ((u32)v)<<16;    return x.f; }
static __device__ __forceinline__ bf_t  f2b(float f){
  union{float f; u32 i;} x; x.f = f;
  return (bf_t)((x.i + 0x7fffu + ((x.i>>16)&1u)) >> 16);   // RNE
}
static __device__ __forceinline__ u32 pack2(float a, float b){
  return (u32)f2b(a) | ((u32)f2b(b) << 16);
}
// fragment-tile index for a row-major [R][384] matrix element (row, k)
static __device__ __forceinline__ size_t ftidx(int row, int k){
  return ((((size_t)(row>>4))*12 + (k>>5))*64 + ((k>>3)&3)*16 + (row&15))*8 + (k&7);
}

// ---------------------------------------------------------------------------
// K0: cast x / qkv_w / proj_w fp32 -> bf16 in FRAGMENT-TILED layout, plus
// conv-weight transpose [96][27]->[27][96] fp32 (last 31 blocks).
// R24 (verified -2.8us): tile-per-wave; one wave owns one 16x32 fragment
// tile -> lane l writes 16B contiguous, wave writes a coalesced 1KB tile.
// ---------------------------------------------------------------------------
#define NA_ (BN_*DIM_)        // 1,204,224
#define NB_ (3*DIM_*DIM_)     //   442,368
#define NC_ (DIM_*DIM_)       //   147,456
#define TILES_X 2352          // (3136/16)*(384/32)
#define TILES_B 864           // (1152/16)*12
#define TILES_C 288           // (384/16)*12
#define CAST_MBLOCKS ((TILES_X+TILES_B+TILES_C)/4)   // 876 exactly

__global__ __launch_bounds__(256) void k_cast(
    const float* __restrict__ a, bf_t* __restrict__ ad,
    const float* __restrict__ b, bf_t* __restrict__ bd,
    const float* __restrict__ c, bf_t* __restrict__ cd,
    const float* __restrict__ wq, const float* __restrict__ wk,
    const float* __restrict__ wv, float* __restrict__ tq,
    float* __restrict__ tk, float* __restrict__ tv){
  if (blockIdx.x < CAST_MBLOCKS){
    const int tile = blockIdx.x*4 + (threadIdx.x >> 6);
    const int lane = threadIdx.x & 63;
    const float* src; bf_t* dst; int tl;
    if (tile < TILES_X)                { src = a; dst = ad; tl = tile; }
    else if (tile < TILES_X + TILES_B) { src = b; dst = bd; tl = tile - TILES_X; }
    else                               { src = c; dst = cd; tl = tile - TILES_X - TILES_B; }
    const int mt = tl / 12, kt = tl % 12;
    const int row = mt*16 + (lane & 15);
    const int k0  = kt*32 + (lane >> 4)*8;
    const float4 v0 = *(const float4*)(src + (size_t)row*DIM_ + k0);
    const float4 v1 = *(const float4*)(src + (size_t)row*DIM_ + k0 + 4);
    const u32 w0 = pack2(v0.x, v0.y), w1 = pack2(v0.z, v0.w);
    const u32 w2 = pack2(v1.x, v1.y), w3 = pack2(v1.z, v1.w);
    *(uint4*)(dst + (size_t)tl*512 + lane*8) = make_uint4(w0, w1, w2, w3);
  } else {
    const int idx = (blockIdx.x - CAST_MBLOCKS)*256 + threadIdx.x;
    if (idx >= 3*HD_*27) return;
    const int t = idx / (HD_*27), rem = idx % (HD_*27);
    const int ch = rem / 27, j = rem % 27;
    const float* s = (t==0)? wq : (t==1)? wk : wv;
    float* d       = (t==0)? tq : (t==1)? tk : tv;
    d[j*HD_ + ch] = s[ch*27 + j];
  }
}

// ---------------------------------------------------------------------------
// K1: QKV GEMM via MFMA, fragment-tiled operands.
// 32-row tile per wave (proven best; R26's 16-row split regressed +5.6us:
// B-reuse halving doubled B-fragment loads -- issue/L2-BW-bound, not
// latency-bound). Scalar-store epilogue (R21/22: LDS staging +1.5us).
// ---------------------------------------------------------------------------
__global__ __launch_bounds__(256) void k_qkv(const bf_t* __restrict__ Xt,
    const bf_t* __restrict__ Wt,
    bf_t* __restrict__ q, bf_t* __restrict__ k, bf_t* __restrict__ v){
  const int wid = threadIdx.x >> 6, lane = threadIdx.x & 63;
  const int wr = wid & 1, wc = wid >> 1;
  const int nl = lane & 15, quad = lane >> 4;
  const int r0 = blockIdx.x*64 + wr*32;
  const int mt0 = r0 >> 4;
  const int nt0 = blockIdx.y*8 + wc*4;
  f32x4 acc[2][4];
  #pragma unroll
  for (int i = 0; i < 2; ++i)
    #pragma unroll
    for (int j = 0; j < 4; ++j) acc[i][j] = (f32x4){0.f,0.f,0.f,0.f};
  const bf_t* A0 = Xt + ((size_t)mt0*12*64 + lane)*8;
  const bf_t* B0 = Wt + ((size_t)nt0*12*64 + lane)*8;
  #pragma unroll 2
  for (int k0 = 0; k0 < 12; ++k0){
    const bf16x8 a0 = *(const bf16x8*)(A0 + k0*512);
    const bf16x8 a1 = *(const bf16x8*)(A0 + 12*512 + k0*512);
    bf16x8 bf[4];
    #pragma unroll
    for (int j = 0; j < 4; ++j) bf[j] = *(const bf16x8*)(B0 + (size_t)(j*12 + k0)*512);
    #pragma unroll
    for (int j = 0; j < 4; ++j){
      acc[0][j] = __builtin_amdgcn_mfma_f32_16x16x32_bf16(a0, bf[j], acc[0][j], 0, 0, 0);
      acc[1][j] = __builtin_amdgcn_mfma_f32_16x16x32_bf16(a1, bf[j], acc[1][j], 0, 0, 0);
    }
  }
  #pragma unroll
  for (int i = 0; i < 2; ++i){
    #pragma unroll
    for (int r = 0; r < 4; ++r){
      const int m  = r0 + i*16 + quad*4 + r;
      const int bb = m / N_, nn = m % N_;
      #pragma unroll
      for (int j = 0; j < 4; ++j){
        const int col = (nt0 + j)*16 + nl;
        const int s = col / DIM_, rem = col - s*DIM_;
        const int head = rem / HD_, hc = rem % HD_;
        bf_t* dst = (s==0) ? q : (s==1) ? k : v;
        dst[((size_t)(bb*NH_ + head)*N_ + nn)*HD_ + hc] = f2b(acc[i][j][r]);
      }
    }
  }
}

static __device__ __forceinline__ void ln_butterfly(
    float v0, float v1, float& mean, float& rstd){
  float s  = v0 + v1;
  float s2 = v0*v0 + v1*v1;
  #pragma unroll
  for (int off = 32; off > 0; off >>= 1){
    s  += __shfl_xor(s,  off);
    s2 += __shfl_xor(s2, off);
  }
  mean = s * (1.f/HD_);
  const float var = fmaxf(s2*(1.f/HD_) - mean*mean, 0.f);
  rstd = rsqrtf(var + 1e-6f);
}

// ---------------------------------------------------------------------------
// K2: LDS-slab pooled conv+LN, 16 tokens/block (4 waves x 4 tokens).
// Halo slab 162 rows (3t x 3h x 18w) x 96ch bf16 = 31.1 KB.
// R16 form (best measured; latency-bound at ~42-44% VALU, 13 waves/CU).
// Falsified alternatives: R14 forced-occupancy (spill), R17 deep pipeline
// (scheduler fight), R19 XCD pinning (FETCH 22->3.9MB, timing-neutral).
// Observed env variance on identical code: 47.6-55.8us.
// ---------------------------------------------------------------------------
union PoolSM {
  bf_t  slab[162][HD_];       // 31,104 B  (phase 1)
  float qtmp[4][4][HD_];      //  6,144 B  (phase 2, sec 0; per-wave)
  u32   vres[16][48];         //  3,072 B  (phase 2, sec 2)
};

__global__ __launch_bounds__(256) void k_pool_slab(
    const bf_t* __restrict__ qr_, const bf_t* __restrict__ kr_, const bf_t* __restrict__ vr_,
    const float* __restrict__ wtq, const float* __restrict__ wtk, const float* __restrict__ wtv,
    const float* __restrict__ gq, const float* __restrict__ bq,
    const float* __restrict__ gk, const float* __restrict__ bk,
    const float* __restrict__ gv, const float* __restrict__ bv,
    const float* __restrict__ rph, const float* __restrict__ rpw,
    const float* __restrict__ rpt,
    bf_t* __restrict__ qp, bf_t* __restrict__ Qaug,
    bf_t* __restrict__ Kt, bf_t* __restrict__ Vtt){
  __shared__ __align__(16) PoolSM sm;
  const int wid = threadIdx.x >> 6, lane = threadIdx.x & 63;
  const int sec = blockIdx.x / 784;
  const int rr_ = blockIdx.x % 784;
  const int bh = rr_ / 98, tok0 = (rr_ % 98)*16;
  const bf_t*  src = (sec==0)? qr_ : (sec==1)? kr_ : vr_;
  const float* wt  = (sec==0)? wtq : (sec==1)? wtk : wtv;
  const float* g   = (sec==0)? gq  : (sec==1)? gk  : gv;
  const float* be  = (sec==0)? bq  : (sec==1)? bk  : bv;
  const bf_t* base = src + (size_t)bh*N_*HD_;

  // per-lane channel pair; first weight trio + LN params overlap staging
  const int c0 = (lane < 48) ? 2*lane : 0;
  float2 wcur[3], wnxt[3];
  #pragma unroll
  for (int dw = 0; dw < 3; ++dw) wcur[dw] = *(const float2*)(wt + dw*HD_ + c0);
  const float gg0 = g[c0], gg1 = g[c0+1], be0 = be[c0], be1 = be[c0+1];

  // ---- staging: batched loads into regs, then LDS writes (vmcnt pipeline) --
  {
    uint4 stg[8];
    #pragma unroll
    for (int it = 0; it < 8; ++it){
      const int li = threadIdx.x + it*256;
      const int lc = (li < 162*12) ? li : (162*12 - 1);
      const int rw = lc / 12, ss = lc % 12;
      const int aa = rw/54, bb2 = (rw%54)/18, cc = rw%18;
      int nn = tok0 + (aa-1)*HW_ + (bb2-1)*W_ + (cc-1);
      nn = min(max(nn, 0), N_-1);
      stg[it] = *(const uint4*)(base + (size_t)nn*HD_ + ss*8);
    }
    #pragma unroll
    for (int it = 0; it < 8; ++it){
      const int li = threadIdx.x + it*256;
      if (li < 162*12){
        const int rw = li / 12, ss = li % 12;
        *(uint4*)&sm.slab[rw][ss*8] = stg[it];
      }
    }
  }
  __syncthreads();

  // token coordinates (wave-uniform) + 27-bit validity masks
  int tt[4], hh[4], ww[4];
  u32 mr[4];
  #pragma unroll
  for (int tk = 0; tk < 4; ++tk){
    const int n = tok0 + wid*4 + tk;
    tt[tk] = n / HW_;
    const int rm = n % HW_;
    hh[tk] = rm / W_; ww[tk] = rm % W_;
    const u32 wb = (ww[tk] > 0 ? 1u : 0u) | 2u | (ww[tk] < W_-1 ? 4u : 0u);
    const u32 h9 = (hh[tk] > 0 ? wb : 0u) | (wb << 3) | (hh[tk] < H_-1 ? (wb << 6) : 0u);
    mr[tk] = (tt[tk] > 0 ? h9 : 0u) | (h9 << 9) | (tt[tk] < T_-1 ? (h9 << 18) : 0u);
  }

  // ---- phase 1: conv, software-pipelined row reads ----
  float v0[4] = {0.f,0.f,0.f,0.f}, v1[4] = {0.f,0.f,0.f,0.f};
  u32 rr[6], rrn[6];
  #pragma unroll
  for (int s = 0; s < 6; ++s) rr[s] = *(const u32*)&sm.slab[wid*4 + s][c0];
  #pragma unroll 1
  for (int j9 = 0; j9 < 9; ++j9){
    if (j9 < 8){
      const int jn = j9 + 1;
      const int rbn = (jn/3)*54 + (jn%3)*18 + wid*4;
      #pragma unroll
      for (int s = 0; s < 6; ++s) rrn[s] = *(const u32*)&sm.slab[rbn + s][c0];
      #pragma unroll
      for (int dw = 0; dw < 3; ++dw)
        wnxt[dw] = *(const float2*)(wt + (jn*3 + dw)*HD_ + c0);
    }
    #pragma unroll
    for (int tk = 0; tk < 4; ++tk){
      #pragma unroll
      for (int dw = 0; dw < 3; ++dw){
        const u32 d = (mr[tk] & (1u << dw)) ? rr[tk+dw] : 0u;
        v0[tk] = fmaf(wcur[dw].x, lo16(d), v0[tk]);
        v1[tk] = fmaf(wcur[dw].y, hi16(d), v1[tk]);
      }
      mr[tk] >>= 3;
    }
    #pragma unroll
    for (int s = 0; s < 6; ++s) rr[s] = rrn[s];
    #pragma unroll
    for (int dw = 0; dw < 3; ++dw) wcur[dw] = wnxt[dw];
  }
  // LayerNorm per token (results stay in v0/v1)
  #pragma unroll
  for (int tk = 0; tk < 4; ++tk){
    float a = v0[tk], b = v1[tk];
    if (lane >= 48){ a = 0.f; b = 0.f; }
    float mean, rstd;
    ln_butterfly(a, b, mean, rstd);
    v0[tk] = (a - mean)*rstd*gg0 + be0;
    v1[tk] = (b - mean)*rstd*gg1 + be1;
  }

  // ---- phase 2: outputs (qtmp/vres overlay slab; barrier before overlay) --
  if (sec == 0){
    __syncthreads();                              // slab -> qtmp overlay
    #pragma unroll
    for (int tk = 0; tk < 4; ++tk){
      const int n = tok0 + wid*4 + tk;
      const int token = bh*N_ + n;
      if (lane < 48){
        ((u32*)qp)  [(size_t)token*48 + lane] = pack2(v0[tk], v1[tk]);
        ((u32*)Qaug)[(size_t)token*80 + lane] = pack2(v0[tk]*QSCALE_LOG2E, v1[tk]*QSCALE_LOG2E);
        *(float2*)&sm.qtmp[wid][tk][c0] = make_float2(v0[tk], v1[tk]);
      }
    }
    // qtmp written/read by the SAME wave -> ordered by lgkmcnt, no barrier
    #pragma unroll
    for (int tk = 0; tk < 4; ++tk){
      const int n = tok0 + wid*4 + tk;
      const int token = bh*N_ + n;
      if (lane < 36){
        const float* tb; int idx;
        if (lane < 14)      { tb = rph; idx = hh[tk] - lane      + 13; }
        else if (lane < 28) { tb = rpw; idx = ww[tk] - (lane-14) + 13; }
        else                { tb = rpt; idx = tt[tk] - (lane-28) +  7; }
        const float4* t4 = (const float4*)(tb + (size_t)idx*HD_);
        const float4* q4 = (const float4*)&sm.qtmp[wid][tk][0];
        float ap[4] = {0.f, 0.f, 0.f, 0.f};
        #pragma unroll
        for (int i = 0; i < 24; ++i){
          const float4 rv = t4[i];
          const float4 qv = q4[i];                 // ds_read_b128 broadcast
          ap[i & 3] = fmaf(qv.x, rv.x,
                      fmaf(qv.y, rv.y,
                      fmaf(qv.z, rv.z,
                      fmaf(qv.w, rv.w, ap[i & 3]))));
        }
        const float acc = (ap[0] + ap[1]) + (ap[2] + ap[3]);
        Qaug[(size_t)token*CAUG_ + HD_ + lane] = f2b(acc * LOG2E);
      } else {
        Qaug[(size_t)token*CAUG_ + HD_ + lane] = 0;
      }
    }
  } else if (sec == 1){
    // no LDS use in this branch -> no barrier needed
    #pragma unroll
    for (int tk = 0; tk < 4; ++tk){
      const int n = tok0 + wid*4 + tk;
      const int tl = n >> 4, nr = n & 15;
      if (lane < 48){
        const size_t idx = ((((size_t)bh*98 + tl)*5 + (lane>>4))*64
                           + ((lane&15)>>2)*16 + nr)*4 + (lane&3);
        ((u32*)Kt)[idx] = pack2(v0[tk], v1[tk]);
      } else {
        const int m = lane - 48;
        u32 pr_[2];
        #pragma unroll
        for (int h2 = 0; h2 < 2; ++h2){
          u32 w_ = 0;
          #pragma unroll
          for (int e = 0; e < 2; ++e){
            const int jj = 4*m + 2*h2 + e;
            bool on = (jj < 14) ? (jj == hh[tk]) : (jj < 28) ? (jj-14 == ww[tk])
                     : (jj < 36) ? (jj-28 == tt[tk]) : false;
            if (on) w_ |= (0x3F80u << (16*e));
          }
          pr_[h2] = w_;
        }
        const size_t bidx = ((((size_t)bh*98 + tl)*5 + (3 + (m>>3)))*64
                            + ((m&7)>>1)*16 + nr)*4 + 2*(m&1);
        *(uint2*)((u32*)Kt + bidx) = make_uint2(pr_[0], pr_[1]);
      }
    }
  } else {
    __syncthreads();                              // slab -> vres overlay
    #pragma unroll
    for (int tk = 0; tk < 4; ++tk){
      if (lane < 48) sm.vres[wid*4 + tk][lane] = pack2(v0[tk], v1[tk]);
    }
    __syncthreads();
    if (threadIdx.x < 2*HD_){
      const int grp = threadIdx.x / HD_, c = threadIdx.x % HD_;
      const int t0g = grp*8;
      u32 o[4];
      #pragma unroll
      for (int i = 0; i < 4; ++i){
        const u32 a = sm.vres[t0g + 2*i][c>>1], b = sm.vres[t0g + 2*i+1][c>>1];
        const u32 ra = (c&1) ? (a >> 16) : (a & 0xffffu);
        const u32 rb = (c&1) ? (b >> 16) : (b & 0xffffu);
        o[i] = ra | (rb << 16);
      }
      const int n0g = tok0 + t0g;
      const int pr = n0g >> 5, qd = (n0g & 31) >> 3;
      bf_t* dst = Vtt + ((((size_t)bh*49 + pr)*6 + (c>>4))*64 + qd*16 + (c&15))*8;
      *(uint4*)dst = make_uint4(o[0], o[1], o[2], o[3]);
    }
  }
}

// ---------------------------------------------------------------------------
// K4: MFMA flash attention, 8-wave in-block split-K, fragment-tiled K/V.
// R25 (verified): phase-A/phase-B combine epilogue -- per-row merge weights
// computed once, vectorized Os/qp reads, one uint2 coalesced store/thread.
// ---------------------------------------------------------------------------
__global__ __launch_bounds__(512) void k_attn(
    const bf_t* __restrict__ Qaug, const bf_t* __restrict__ Kt,
    const bf_t* __restrict__ Vtt, const bf_t* __restrict__ qp,
    bf_t* __restrict__ attb){
  __shared__ __align__(16) short Pb[8][16][40];   // per-wave P tile (+8 pad)
  __shared__ bf_t Os[8][16][96];                  // per-wave partial O (bf16)
  __shared__ float ms[8][16], ls[8][16];          // per-wave partial m, l
  __shared__ float wts[16][8];                    // merged per-row weights
  const int wid = threadIdx.x >> 6, lane = threadIdx.x & 63;
  const int bh = blockIdx.x / 98, qt = blockIdx.x % 98;
  const int q0 = qt*16;
  const int nl = lane & 15, quad = lane >> 4;

  bf16x8 qa[5];
  {
    const bf_t* Qrow = Qaug + ((size_t)bh*N_ + q0 + nl)*CAUG_ + quad*8;
    #pragma unroll
    for (int i = 0; i < 5; ++i) qa[i] = *(const bf16x8*)(Qrow + i*32);
  }
  short* Pw = &Pb[wid][0][0];

  f32x4 O[6];
  #pragma unroll
  for (int i = 0; i < 6; ++i) O[i] = (f32x4){0.f,0.f,0.f,0.f};
  float mc[4]   = {0.f,0.f,0.f,0.f};
  float rmax[4] = {-3e38f,-3e38f,-3e38f,-3e38f};
  float l[4]    = {0.f,0.f,0.f,0.f};

  auto s_tile = [&](int tl, int half){
    const bf_t* Kp = Kt + (((size_t)bh*98 + tl)*5*64 + lane)*8;
    f32x4 s = (f32x4){0.f,0.f,0.f,0.f};
    #pragma unroll
    for (int i = 0; i < 5; ++i)
      s = __builtin_amdgcn_mfma_f32_16x16x32_bf16(qa[i], *(const bf16x8*)(Kp + i*512), s, 0, 0, 0);
    #pragma unroll
    for (int r = 0; r < 4; ++r){
      rmax[r] = fmaxf(rmax[r], s[r]);
      const float p = exp2f(s[r] - mc[r]);
      l[r] += p;
      Pw[(quad*4 + r)*40 + half*16 + nl] = (short)f2b(p);
    }
  };
  auto rescale = [&](){
    #pragma unroll
    for (int r = 0; r < 4; ++r){
      float tm = rmax[r];
      tm = fmaxf(tm, __shfl_xor(tm, 1));
      tm = fmaxf(tm, __shfl_xor(tm, 2));
      tm = fmaxf(tm, __shfl_xor(tm, 4));
      tm = fmaxf(tm, __shfl_xor(tm, 8));
      const float mn = fmaxf(mc[r], tm);
      const float al = exp2f(mc[r] - mn);
      mc[r] = mn; l[r] *= al;
      #pragma unroll
      for (int ct = 0; ct < 6; ++ct) O[ct][r] *= al;
    }
  };

  const int p0 = (wid == 0) ? 0 : (7 + 6*(wid-1));
  const int npairs = (wid == 0) ? 7 : 6;
  #pragma unroll 1
  for (int pi = 0; pi < npairs; ++pi){
    const int kp = p0 + pi;
    s_tile(2*kp,     0);
    s_tile(2*kp + 1, 1);
    const bf16x8 pa = *(const bf16x8*)(Pw + nl*40 + quad*8);
    const bf_t* Vp = Vtt + (((size_t)bh*49 + kp)*6*64 + lane)*8;
    #pragma unroll
    for (int ct = 0; ct < 6; ++ct)
      O[ct] = __builtin_amdgcn_mfma_f32_16x16x32_bf16(pa, *(const bf16x8*)(Vp + ct*512), O[ct], 0, 0, 0);
    if (pi == npairs-1) rescale();
  }

  #pragma unroll
  for (int r = 0; r < 4; ++r){
    float ls_ = l[r];
    ls_ += __shfl_xor(ls_, 1); ls_ += __shfl_xor(ls_, 2);
    ls_ += __shfl_xor(ls_, 4); ls_ += __shfl_xor(ls_, 8);
    if (nl == 0){ ms[wid][quad*4 + r] = mc[r]; ls[wid][quad*4 + r] = ls_; }
    #pragma unroll
    for (int ct = 0; ct < 6; ++ct) Os[wid][quad*4 + r][ct*16 + nl] = f2b(O[ct][r]);
  }
  __syncthreads();

  // ---- phase A: per-row merge weights (once, folded with 1/L) ----
  if (threadIdx.x < 16){
    const int row = threadIdx.x;
    float mx = -3e38f;
    #pragma unroll
    for (int w = 0; w < 8; ++w) mx = fmaxf(mx, ms[w][row]);
    float wv[8]; float L = 0.f;
    #pragma unroll
    for (int w = 0; w < 8; ++w){
      wv[w] = exp2f(ms[w][row] - mx);
      L = fmaf(wv[w], ls[w][row], L);
    }
    const float rL = 1.f / L;
    #pragma unroll
    for (int w = 0; w < 8; ++w) wts[row][w] = wv[w]*rL;
  }
  __syncthreads();

  // ---- phase B: 384 threads x 4 cols, vectorized reads + uint2 store ----
  if (threadIdx.x < 384){
    const int row = threadIdx.x / 24, gg = threadIdx.x % 24;
    const int col0 = gg*4;
    float w8[8];
    #pragma unroll
    for (int w = 0; w < 8; ++w) w8[w] = wts[row][w];
    float a0 = 0.f, a1 = 0.f, a2 = 0.f, a3 = 0.f;
    #pragma unroll
    for (int w = 0; w < 8; ++w){
      const ushort4 o4 = *(const ushort4*)&Os[w][row][col0];
      a0 = fmaf(w8[w], b2f(o4.x), a0);
      a1 = fmaf(w8[w], b2f(o4.y), a1);
      a2 = fmaf(w8[w], b2f(o4.z), a2);
      a3 = fmaf(w8[w], b2f(o4.w), a3);
    }
    const ushort4 qv = *(const ushort4*)(qp + ((size_t)bh*N_ + q0 + row)*HD_ + col0);
    const u32 lo = pack2(a0 + b2f(qv.x), a1 + b2f(qv.y));
    const u32 hi = pack2(a2 + b2f(qv.z), a3 + b2f(qv.w));
    const int bb = bh >> 2, head = bh & 3;
    const int grow0 = bb*N_ + q0;                 // multiple of 16
    *(uint2*)(attb + ftidx(grow0 + row, head*HD_ + col0)) = make_uint2(lo, hi);
  }
}

// ---------------------------------------------------------------------------
// K5: output projection via MFMA, fragment-tiled A (attb) and B (Wpt).
// 32-row tile per wave (proven best; see k_qkv note).
// ---------------------------------------------------------------------------
__global__ __launch_bounds__(256) void k_proj(const bf_t* __restrict__ At,
    const bf_t* __restrict__ Wpt, const float* __restrict__ pb,
    float* __restrict__ out){
  const int wid = threadIdx.x >> 6, lane = threadIdx.x & 63;
  const int wr = wid & 1, wc = wid >> 1;
  const int nl = lane & 15, quad = lane >> 4;
  const int r0 = blockIdx.x*64 + wr*32;
  const int mt0 = r0 >> 4;
  const int nt0 = blockIdx.y*8 + wc*4;
  f32x4 acc[2][4];
  #pragma unroll
  for (int i = 0; i < 2; ++i)
    #pragma unroll
    for (int j = 0; j < 4; ++j) acc[i][j] = (f32x4){0.f,0.f,0.f,0.f};
  const bf_t* A0 = At  + ((size_t)mt0*12*64 + lane)*8;
  const bf_t* B0 = Wpt + ((size_t)nt0*12*64 + lane)*8;
  #pragma unroll 2
  for (int k0 = 0; k0 < 12; ++k0){
    const bf16x8 a0 = *(const bf16x8*)(A0 + k0*512);
    const bf16x8 a1 = *(const bf16x8*)(A0 + 12*512 + k0*512);
    bf16x8 bf[4];
    #pragma unroll
    for (int j = 0; j < 4; ++j) bf[j] = *(const bf16x8*)(B0 + (size_t)(j*12 + k0)*512);
    #pragma unroll
    for (int j = 0; j < 4; ++j){
      acc[0][j] = __builtin_amdgcn_mfma_f32_16x16x32_bf16(a0, bf[j], acc[0][j], 0, 0, 0);
      acc[1][j] = __builtin_amdgcn_mfma_f32_16x16x32_bf16(a1, bf[j], acc[1][j], 0, 0, 0);
    }
  }
  #pragma unroll
  for (int i = 0; i < 2; ++i){
    #pragma unroll
    for (int r = 0; r < 4; ++r){
      const int m = r0 + i*16 + quad*4 + r;
      #pragma unroll
      for (int j = 0; j < 4; ++j){
        const int col = (nt0 + j)*16 + nl;
        out[(size_t)m*DIM_ + col] = acc[i][j][r] + pb[col];
      }
    }
  }
}

// ---------------------------------------------------------------------------
extern "C" void kernel_launch(void* const* d_in, const int* in_sizes, int n_in,
                              void* d_out, int out_size, void* d_ws, size_t ws_size,
                              hipStream_t stream){
  const float* x      = (const float*)d_in[0];
  const float* qkv_w  = (const float*)d_in[1];
  const float* proj_w = (const float*)d_in[2];
  const float* proj_b = (const float*)d_in[3];
  const float* pqw    = (const float*)d_in[4];
  const float* pkw    = (const float*)d_in[5];
  const float* pvw    = (const float*)d_in[6];
  const float* nqw    = (const float*)d_in[7];
  const float* nqb    = (const float*)d_in[8];
  const float* nkw    = (const float*)d_in[9];
  const float* nkb    = (const float*)d_in[10];
  const float* nvw    = (const float*)d_in[11];
  const float* nvb    = (const float*)d_in[12];
  const float* rph    = (const float*)d_in[13];
  const float* rpw    = (const float*)d_in[14];
  const float* rpt    = (const float*)d_in[15];

  // Workspace (bytes), ~23.7 MB total. attb overlays raw_q after pooling.
  char* p = (char*)d_ws;
  const size_t RAW = (size_t)BH_*N_*HD_*2;       // 2,408,448 B
  const size_t AUG = (size_t)BH_*N_*CAUG_*2;     // 4,014,080 B
  bf_t* xb     = (bf_t*)(p);                     // frag-tiled
  bf_t* wqkvb  = (bf_t*)(p + RAW);               // frag-tiled
  bf_t* wprojb = (bf_t*)(p + RAW + 884736);      // frag-tiled
  char* p2 = p + RAW + 884736 + 294912;
  bf_t* raw_q  = (bf_t*)(p2);
  bf_t* raw_k  = (bf_t*)(p2 + RAW);
  bf_t* raw_v  = (bf_t*)(p2 + 2*RAW);
  bf_t* attb   = raw_q;                          // overlays raw_q (frag-tiled)
  bf_t* qp     = (bf_t*)(p2 + 3*RAW);
  bf_t* Qaug   = (bf_t*)(p2 + 4*RAW);
  bf_t* Kt     = (bf_t*)(p2 + 4*RAW + AUG);      // tiled Kaug
  bf_t* Vtt    = (bf_t*)(p2 + 4*RAW + 2*AUG);    // tiled V
  float* wtq   = (float*)(p2 + 4*RAW + 2*AUG + RAW);   // 3 x 27x96 fp32
  float* wtk   = wtq + 27*HD_;
  float* wtv   = wtk + 27*HD_;

  k_cast     <<<CAST_MBLOCKS + 31, 256, 0, stream>>>(x, xb, qkv_w, wqkvb, proj_w, wprojb,
                                                     pqw, pkw, pvw, wtq, wtk, wtv);
  k_qkv      <<<dim3(BN_/64, 9),  256, 0, stream>>>(xb, wqkvb, raw_q, raw_k, raw_v);
  k_pool_slab<<<3*784,            256, 0, stream>>>(raw_q, raw_k, raw_v,
                                                    wtq, wtk, wtv,
                                                    nqw, nqb, nkw, nkb, nvw, nvb,
                                                    rph, rpw, rpt,
                                                    qp, Qaug, Kt, Vtt);
  k_attn     <<<BH_*98,           512, 0, stream>>>(Qaug, Kt, Vtt, qp, attb);
  k_proj     <<<dim3(BN_/64, 3),  256, 0, stream>>>(attb, wprojb, proj_b, (float*)d_out);
}